// Round 8
// baseline (433.500 us; speedup 1.0000x reference)
//
#include <hip/hip_runtime.h>

#define D_DIM 256
#define K_CODES 1024
#define MARGIN 4e-4f
#define CAP 32

typedef __attribute__((ext_vector_type(8))) short short8;
typedef __attribute__((ext_vector_type(4))) float f32x4;

union Pack8 { unsigned int u[4]; short8 s8; };

// RNE f32 -> bf16 bits (finite inputs only; self-contained, deterministic)
__device__ __forceinline__ unsigned int bfr(float x) {
    unsigned int u = __float_as_uint(x);
    return (u + 0x7FFFu + ((u >> 16) & 1u)) >> 16;
}
__device__ __forceinline__ float bf2f(unsigned int b) {
    return __uint_as_float(b << 16);
}

// ---------------------------------------------------------------------------
// Fused prep: [0,128) z2 | [128,132) e2 | [132,164) e bf16-split |
//             [164,180) rowKey init (+lossAcc zero)
// NUMERICS: z2/e2 chains bit-identical to the validated versions.
// ---------------------------------------------------------------------------
__global__ __launch_bounds__(256) void k_prep(const float* __restrict__ z,
                                              const float* __restrict__ e,
                                              float* __restrict__ z2,
                                              float* __restrict__ e2,
                                              unsigned short* __restrict__ ehi,
                                              unsigned short* __restrict__ elo,
                                              unsigned long long* __restrict__ rowKey,
                                              float* __restrict__ lossAcc) {
    const int bi = blockIdx.x;
    const int t  = threadIdx.x;
    if (bi < 128) {                    // ---- z2 ----
        int n = bi * 256 + t;
        int b = n >> 10, nl = n & 1023;
        const float* p = z + (size_t)b * (D_DIM * 1024) + nl;
        float s = 0.f;
#pragma unroll 8
        for (int d = 0; d < D_DIM; ++d) {
            float v = p[(size_t)d * 1024];
            s = fmaf(v, v, s);
        }
        z2[n] = s;
    } else if (bi < 132) {             // ---- e2 ----
        int k = (bi - 128) * 256 + t;
        const float4* p = (const float4*)(e + (size_t)k * D_DIM);
        float s = 0.f;
#pragma unroll 4
        for (int c = 0; c < D_DIM / 4; ++c) {
            float4 v = p[c];
            s = fmaf(v.x, v.x, s); s = fmaf(v.y, v.y, s);
            s = fmaf(v.z, v.z, s); s = fmaf(v.w, v.w, s);
        }
        e2[k] = s;
    } else if (bi < 164) {             // ---- e split ----
        if (bi == 132 && t == 0) lossAcc[0] = 0.f;
        int base = (bi - 132) * 8192;
#pragma unroll 8
        for (int j = 0; j < 32; ++j) {
            int idx = base + j * 256 + t;
            float v = e[idx];
            unsigned int hb = bfr(v);
            unsigned int lb = bfr(v - bf2f(hb));
            ehi[idx] = (unsigned short)hb;
            elo[idx] = (unsigned short)lb;
        }
    } else {                           // ---- rowKey init ----
        int base = (bi - 164) * 2048;
#pragma unroll
        for (int j = 0; j < 8; ++j)
            rowKey[base + j * 256 + t] = 0xFFFFFFFFFFFFFFFFULL;
    }
}

// ---------------------------------------------------------------------------
// MFMA shortlist + exact rescore, code-quarter partitioned (occupancy).
// ROUND-7 BUG FIXED HERE: CAP was 16 while the per-quarter stale-threshold
// capture process has lambda ~ 5 => P(overflow) ~ 5e-5 per quarter-row ~ 7
// rows dataset-wide silently dropped candidates (incl. the argmin).
// Fix: (a) CAP 32 (P(>32|lam~5) ~ 3e-15 -> ~4e-10 dataset-wide);
//      (b) deterministic fallback: any row whose raw cnt exceeded CAP gets a
//          FULL exact scan of this quarter's 256 codes folded into its key —
//          shortlist completeness no longer rests on a tail bound.
// CORRECTNESS otherwise as round 7 (superset capture proof + exact rescore):
// approx scores bitwise = round 6's (validated); every candidate rescored
// with the validated fp32 path (ascending-d FMA chain, dist = fmaf(-2, ze,
// fl(z2+e2))); merged via packed (distbits<<32|k) atomicMin == lexicographic
// (dist, k) == np argmin first-index tie-break (dist > 0 always).
// MFMA layouts (validated round 6, absmax 0): C/D col=lane&15,
// row=(lane>>4)*4+reg; A row=lane&15, k=(lane>>4)*8+j; B col=lane&15, same k.
// ---------------------------------------------------------------------------
__global__ __launch_bounds__(256, 2) void k_approx(
        const float* __restrict__ z, const float* __restrict__ e,
        const unsigned short* __restrict__ ehi,
        const unsigned short* __restrict__ elo,
        const float* __restrict__ z2, const float* __restrict__ e2,
        unsigned long long* __restrict__ rowKey) {
    __shared__ int cnt[4][16];
    __shared__ int candK[4][16][CAP];

    const int t    = threadIdx.x;
    const int lane = t & 63;
    const int w    = t >> 6;
    const int col  = lane & 15;   // A-row / B-code lane role
    const int kg   = lane >> 4;   // k-group 0..3

    const int q   = blockIdx.x & 3;              // code quarter
    const int rg  = (blockIdx.x >> 2) * 4 + w;   // row-group 0..2047
    const int n0  = rg * 16;
    const int b   = n0 >> 10;
    const int nl0 = n0 & 1023;
    const int ct0 = q * 16;                      // first tile of quarter

    if (t < 64) cnt[t >> 4][t & 15] = 0;
    __syncthreads();

    // ---- A-panel: lane holds row 'col', d = s*32 + kg*8 + j ----
    const float* zp = z + (size_t)b * (D_DIM * 1024) + nl0 + col;
    short8 ah[8], al[8];
#pragma unroll
    for (int s = 0; s < 8; ++s) {
        float f[8];
#pragma unroll
        for (int j = 0; j < 8; ++j)
            f[j] = zp[(size_t)(s * 32 + kg * 8 + j) * 1024];
        Pack8 ph, pl;
#pragma unroll
        for (int p = 0; p < 4; ++p) {
            unsigned int h0 = bfr(f[2 * p]);
            unsigned int h1 = bfr(f[2 * p + 1]);
            unsigned int l0 = bfr(f[2 * p]     - bf2f(h0));
            unsigned int l1 = bfr(f[2 * p + 1] - bf2f(h1));
            ph.u[p] = h0 | (h1 << 16);
            pl.u[p] = l0 | (l1 << 16);
        }
        ah[s] = ph.s8;
        al[s] = pl.s8;
    }

    float m[4] = { 1e30f, 1e30f, 1e30f, 1e30f };

#define SHARE_M()                                                        \
    do {                                                                 \
        _Pragma("unroll")                                                \
        for (int r = 0; r < 4; ++r) {                                    \
            _Pragma("unroll")                                            \
            for (int dlt = 1; dlt < 16; dlt <<= 1)                       \
                m[r] = fminf(m[r], __shfl_xor(m[r], dlt, 64));           \
        }                                                                \
    } while (0)

#pragma unroll 2
    for (int ci = 0; ci < 16; ++ci) {
        const int ct = ct0 + ci;
        const unsigned short* bh = ehi + (size_t)(ct * 16 + col) * D_DIM + kg * 8;
        const unsigned short* bl = elo + (size_t)(ct * 16 + col) * D_DIM + kg * 8;
        f32x4 accA = { 0.f, 0.f, 0.f, 0.f };
        f32x4 accB = { 0.f, 0.f, 0.f, 0.f };
#pragma unroll
        for (int s = 0; s < 8; ++s) {
            short8 vh = *(const short8*)(bh + s * 32);
            short8 vl = *(const short8*)(bl + s * 32);
            if (s & 1) {
                accB = __builtin_amdgcn_mfma_f32_16x16x32_bf16(ah[s], vh, accB, 0, 0, 0);
                accB = __builtin_amdgcn_mfma_f32_16x16x32_bf16(al[s], vh, accB, 0, 0, 0);
                accB = __builtin_amdgcn_mfma_f32_16x16x32_bf16(ah[s], vl, accB, 0, 0, 0);
            } else {
                accA = __builtin_amdgcn_mfma_f32_16x16x32_bf16(ah[s], vh, accA, 0, 0, 0);
                accA = __builtin_amdgcn_mfma_f32_16x16x32_bf16(al[s], vh, accA, 0, 0, 0);
                accA = __builtin_amdgcn_mfma_f32_16x16x32_bf16(ah[s], vl, accA, 0, 0, 0);
            }
        }
        float e2k = e2[ct * 16 + col];
        float s4[4];
#pragma unroll
        for (int r = 0; r < 4; ++r) {
            float zev = accA[r] + accB[r];
            s4[r] = fmaf(-2.f, zev, e2k);        // approx score (z2-free)
        }
        if (ci == 0) {                           // seed + share before capture
#pragma unroll
            for (int r = 0; r < 4; ++r) m[r] = s4[r];
            SHARE_M();
        }
#pragma unroll
        for (int r = 0; r < 4; ++r) {
            if (s4[r] <= m[r] + MARGIN) {
                int rl = kg * 4 + r;
                int slot = atomicAdd(&cnt[w][rl], 1);
                if (slot < CAP) candK[w][rl][slot] = ct * 16 + col;
            }
        }
#pragma unroll
        for (int r = 0; r < 4; ++r) m[r] = fminf(m[r], s4[r]);
        if ((ci & 1) && ci < 15) SHARE_M();
    }
#undef SHARE_M

    __syncthreads();

    // ---- exact rescore of ALL captured candidates, packed-key merge ----
    const int rl = col;
    const int n  = n0 + rl;
    const int cntRaw = cnt[w][rl];
    const int cntr = min(cntRaw, CAP);
    const float z2r = z2[n];
    const float* zrow = z + (size_t)b * (D_DIM * 1024) + (n & 1023);
    unsigned long long key = 0xFFFFFFFFFFFFFFFFULL;
    for (int i = 0; i < 8; ++i) {
        int ci = kg + i * 4;
        bool act = ci < cntr;
        if (!__any(act)) break;
        if (act) {
            int k = candK[w][rl][ci];
            const float* er = e + (size_t)k * D_DIM;
            float ze = 0.f;
#pragma unroll 8
            for (int d = 0; d < D_DIM; ++d)
                ze = fmaf(zrow[(size_t)d * 1024], er[d], ze);
            float t1 = z2r + e2[k];              // fl(z2 + e2)
            float dist = fmaf(-2.f, ze, t1);     // fl(t1 - 2*ze)
            unsigned long long kk =
                ((unsigned long long)__float_as_uint(dist) << 32) |
                (unsigned int)k;
            if (kk < key) key = kk;
        }
    }
    // ---- overflow fallback: full exact scan of this quarter for that row ----
    {
        bool ovf = (cntRaw > CAP);
        if (__any(ovf)) {
            if (ovf) {
                for (int c = 0; c < 64; ++c) {
                    int k = q * 256 + kg * 64 + c;
                    const float* er = e + (size_t)k * D_DIM;
                    float ze = 0.f;
#pragma unroll 8
                    for (int d = 0; d < D_DIM; ++d)
                        ze = fmaf(zrow[(size_t)d * 1024], er[d], ze);
                    float t1 = z2r + e2[k];
                    float dist = fmaf(-2.f, ze, t1);
                    unsigned long long kk =
                        ((unsigned long long)__float_as_uint(dist) << 32) |
                        (unsigned int)k;
                    if (kk < key) key = kk;
                }
            }
        }
    }
    { unsigned long long o = __shfl_xor(key, 16, 64); if (o < key) key = o;
      o = __shfl_xor(key, 32, 64);                    if (o < key) key = o; }
    if (kg == 0 && key != 0xFFFFFFFFFFFFFFFFULL)
        atomicMin(&rowKey[n], key);
}

// ---------------------------------------------------------------------------
// Epilogue: resolve idx from rowKey + z_q gather + straight-through out +
// loss partial sums (validated round 4/5 version).
// ---------------------------------------------------------------------------
__global__ __launch_bounds__(256) void k_epilogue(const float* __restrict__ z,
                                                  const float* __restrict__ e,
                                                  const unsigned long long* __restrict__ rowKey,
                                                  float* __restrict__ outZ,
                                                  float* __restrict__ outIdx,
                                                  float* __restrict__ lossAcc) {
    __shared__ float4 zq4[64][64];
    __shared__ int idxs[64];
    const int t = threadIdx.x;
    const int n0 = blockIdx.x * 64;
    const int b = n0 >> 10, nl0 = n0 & 1023;

    if (t < 64) {
        unsigned long long key = rowKey[n0 + t];
        int bi = (int)(unsigned int)(key & 0xFFFFFFFFULL);
        idxs[t] = bi;
        outIdx[n0 + t] = (float)bi;
    }
    __syncthreads();

#pragma unroll
    for (int j = 0; j < 16; ++j) {
        int flat = j * 256 + t;
        int i  = flat >> 6;
        int c4 = flat & 63;
        float4 v = *(const float4*)(e + (size_t)idxs[i] * D_DIM + c4 * 4);
        zq4[i][c4 ^ (i & 7)] = v;
    }
    __syncthreads();

    const int i  = t & 63;
    const int dg = t >> 6;
    const float* zp = z    + (size_t)b * (D_DIM * 1024) + nl0 + i;
    float*       op = outZ + (size_t)b * (D_DIM * 1024) + nl0 + i;
    float s = 0.f;
#pragma unroll 4
    for (int c = 0; c < 16; ++c) {
        int c4 = dg * 16 + c;
        float4 qv = zq4[i][c4 ^ (i & 7)];
        int d = c4 * 4;
        float zv, df;
        zv = zp[(size_t)(d + 0) * 1024]; df = qv.x - zv; s = fmaf(df, df, s); op[(size_t)(d + 0) * 1024] = zv + df;
        zv = zp[(size_t)(d + 1) * 1024]; df = qv.y - zv; s = fmaf(df, df, s); op[(size_t)(d + 1) * 1024] = zv + df;
        zv = zp[(size_t)(d + 2) * 1024]; df = qv.z - zv; s = fmaf(df, df, s); op[(size_t)(d + 2) * 1024] = zv + df;
        zv = zp[(size_t)(d + 3) * 1024]; df = qv.w - zv; s = fmaf(df, df, s); op[(size_t)(d + 3) * 1024] = zv + df;
    }
#pragma unroll
    for (int off = 32; off > 0; off >>= 1) s += __shfl_down(s, off, 64);
    if ((t & 63) == 0) atomicAdd(lossAcc, s);
}

__global__ void k_final(const float* __restrict__ lossAcc,
                        float* __restrict__ outLoss) {
    float m = lossAcc[0] * (1.0f / 8388608.0f);
    outLoss[0] = m + 0.25f * m;
}

// ---------------------------------------------------------------------------
extern "C" void kernel_launch(void* const* d_in, const int* in_sizes, int n_in,
                              void* d_out, int out_size, void* d_ws, size_t ws_size,
                              hipStream_t stream) {
    const float* z = (const float*)d_in[0];   // (32,256,32,32)
    const float* e = (const float*)d_in[1];   // (1024,256)
    float* out     = (float*)d_out;
    float* outIdx  = out + 8388608;
    float* outLoss = out + 8421376;

    float* z2      = (float*)d_ws;                        // 32768 f
    float* e2      = z2 + 32768;                          // 1024 f
    float* lossAcc = e2 + 1024;                           // 1 f
    uintptr_t p = (uintptr_t)(lossAcc + 1);
    p = (p + 255) & ~(uintptr_t)255;
    unsigned long long* rowKey = (unsigned long long*)p;  // 32768 u64
    unsigned short* ehi = (unsigned short*)(rowKey + 32768);  // 262144 u16
    unsigned short* elo = ehi + 262144;                       // 262144 u16

    k_prep<<<180, 256, 0, stream>>>(z, e, z2, e2, ehi, elo, rowKey, lossAcc);
    k_approx<<<2048, 256, 0, stream>>>(z, e, ehi, elo, z2, e2, rowKey);
    k_epilogue<<<512, 256, 0, stream>>>(z, e, rowKey, out, outIdx, lossAcc);
    k_final<<<1, 1, 0, stream>>>(lossAcc, outLoss);
}

// Round 9
// 359.739 us; speedup vs baseline: 1.2050x; 1.2050x over previous
//
#include <hip/hip_runtime.h>

#define D_DIM 256
#define K_CODES 1024
#define MARGIN 4e-4f
#define RCAP 32

typedef __attribute__((ext_vector_type(8))) short short8;
typedef __attribute__((ext_vector_type(4))) float f32x4;

// RNE f32 -> bf16 bits (finite inputs; validated rounds 6-8)
__device__ __forceinline__ unsigned int bfr(float x) {
    unsigned int u = __float_as_uint(x);
    return (u + 0x7FFFu + ((u >> 16) & 1u)) >> 16;
}
__device__ __forceinline__ float bf2f(unsigned int b) {
    return __uint_as_float(b << 16);
}
__device__ __forceinline__ void gload16(const void* g, void* l) {
    __builtin_amdgcn_global_load_lds(
        (const __attribute__((address_space(1))) void*)g,
        (__attribute__((address_space(3))) void*)l, 16, 0, 0);
}

// ---------------------------------------------------------------------------
// k_prep: [0,128) z2 | [128,132) e2 | [132,2180) z split+transpose+swz |
//         [2180,2196) e split+swz | [2196,2228) rowCnt zero (+lossAcc)
// Split layout: zhi/zlo = u16 [32768][256] row-major, ehi/elo = u16 [1024][256],
// with 16B-slot XOR swizzle baked in: within each 64-d slab, storage slot
// s' holds original slot s'^ (row&7)  (8 slots of 8 bf16). This makes the
// linear global_load_lds fill of k_score's LDS tiles bank-conflict-free
// (2-way) on ds_read_b128 (rule #21: swizzle the SOURCE, keep dest linear).
// NUMERICS: z2/e2 ascending chains bit-identical to validated versions.
// ---------------------------------------------------------------------------
__global__ __launch_bounds__(256) void k_prep(const float* __restrict__ z,
                                              const float* __restrict__ e,
                                              float* __restrict__ z2,
                                              float* __restrict__ e2,
                                              unsigned short* __restrict__ zhi,
                                              unsigned short* __restrict__ zlo,
                                              unsigned short* __restrict__ ehi,
                                              unsigned short* __restrict__ elo,
                                              int* __restrict__ rowCnt,
                                              float* __restrict__ lossAcc) {
    __shared__ float tile[64][65];
    const int bi = blockIdx.x;
    const int t  = threadIdx.x;
    if (bi < 128) {                    // ---- z2 ----
        int n = bi * 256 + t;
        int b = n >> 10, nl = n & 1023;
        const float* p = z + (size_t)b * (D_DIM * 1024) + nl;
        float s = 0.f;
#pragma unroll 8
        for (int d = 0; d < D_DIM; ++d) {
            float v = p[(size_t)d * 1024];
            s = fmaf(v, v, s);
        }
        z2[n] = s;
    } else if (bi < 132) {             // ---- e2 ----
        int k = (bi - 128) * 256 + t;
        const float4* p = (const float4*)(e + (size_t)k * D_DIM);
        float s = 0.f;
#pragma unroll 4
        for (int c = 0; c < D_DIM / 4; ++c) {
            float4 v = p[c];
            s = fmaf(v.x, v.x, s); s = fmaf(v.y, v.y, s);
            s = fmaf(v.z, v.z, s); s = fmaf(v.w, v.w, s);
        }
        e2[k] = s;
    } else if (bi < 2180) {            // ---- z split + transpose + swizzle ----
        int bb = bi - 132;
        int n0 = (bb & 511) * 64;
        int d0 = (bb >> 9) * 64;       // slab-aligned
        int b = n0 >> 10, nl0 = n0 & 1023;
#pragma unroll 4
        for (int i = 0; i < 16; ++i) {
            int flat = i * 256 + t;
            int dd = flat >> 6, j = flat & 63;
            tile[dd][j] = z[(size_t)b * (D_DIM * 1024) +
                            (size_t)(d0 + dd) * 1024 + nl0 + j];
        }
        __syncthreads();
#pragma unroll
        for (int i = 0; i < 4; ++i) {
            int flat = i * 256 + t;
            int row = flat >> 4, ch = flat & 15;
            int s8p = ch >> 1, half = ch & 1;
            int s8  = s8p ^ (row & 7);           // n0 mult 64 => (n&7)==(row&7)
            int ddl = s8 * 8 + half * 4;
            unsigned int h[4], l[4];
#pragma unroll
            for (int m2 = 0; m2 < 4; ++m2) {
                float v = tile[ddl + m2][row];
                h[m2] = bfr(v);
                l[m2] = bfr(v - bf2f(h[m2]));
            }
            uint2 ph = { h[0] | (h[1] << 16), h[2] | (h[3] << 16) };
            uint2 pl = { l[0] | (l[1] << 16), l[2] | (l[3] << 16) };
            size_t off = (size_t)(n0 + row) * 256 + d0 + s8p * 8 + half * 4;
            *(uint2*)(zhi + off) = ph;
            *(uint2*)(zlo + off) = pl;
        }
    } else if (bi < 2196) {            // ---- e split + swizzle ----
        int k0 = (bi - 2180) * 64;
#pragma unroll 4
        for (int i = 0; i < 16; ++i) {
            int flat = i * 256 + t;
            int row = flat >> 6, ch = flat & 63;
            int slab = ch >> 4, s8p = (ch >> 1) & 7, half = ch & 1;
            int s8 = s8p ^ (row & 7);            // k0 mult 64
            int d  = slab * 64 + s8 * 8 + half * 4;
            float4 v = *(const float4*)(e + (size_t)(k0 + row) * 256 + d);
            unsigned int h0 = bfr(v.x), h1 = bfr(v.y), h2 = bfr(v.z), h3 = bfr(v.w);
            unsigned int l0 = bfr(v.x - bf2f(h0)), l1 = bfr(v.y - bf2f(h1));
            unsigned int l2 = bfr(v.z - bf2f(h2)), l3 = bfr(v.w - bf2f(h3));
            uint2 ph = { h0 | (h1 << 16), h2 | (h3 << 16) };
            uint2 pl = { l0 | (l1 << 16), l2 | (l3 << 16) };
            size_t off = (size_t)(k0 + row) * 256 + slab * 64 + s8p * 8 + half * 4;
            *(uint2*)(ehi + off) = ph;
            *(uint2*)(elo + off) = pl;
        }
    } else {                           // ---- rowCnt zero ----
        int bb = bi - 2196;            // 0..31
        if (bb == 0 && t == 0) lossAcc[0] = 0.f;
#pragma unroll
        for (int i = 0; i < 4; ++i)
            rowCnt[bb * 1024 + i * 256 + t] = 0;
    }
}

// ---------------------------------------------------------------------------
// k_score: split-bf16 MFMA GEMM, 128 rows x 128 codes x K=256 per block.
// 4 waves (2x2), wave tile 64x64 = 16 frags; per k-step 3 split-MFMAs/frag
// (acc += ah*bh + al*bh + ah*bl; dropped ll term <= 6e-7). BK=64 slabs via
// global_load_lds (16B), round-2 2-barrier cadence, LDS 64 KB -> 2 blk/CU.
// ds_reads hit the pre-swizzled layout: slot' = (ks*4+kq) ^ (row&7) -> 2-way.
// Epilogue: per-row TRUE min over the wave's 64 codes (shfl over c-lanes),
// capture s <= min+MARGIN into global per-row list. Superset proof: for the
// chunk holding the ref argmin k*, s_a(k*) <= chunkmin_a + 2*eps (eps =
// approx+fp32-eval error ~4.5e-5), MARGIN=4e-4 >= 2*eps. Overflow (cnt>RCAP)
// handled deterministically in k_select. No launch_bounds min-waves: let the
// allocator avoid spill (rounds 3/5 lesson).
// MFMA layouts validated r6/r8: A row=lane&15, k=(lane>>4)*8+j; B col=lane&15;
// C/D col=lane&15, row=(lane>>4)*4+reg.
// ---------------------------------------------------------------------------
__global__ __launch_bounds__(256) void k_score(
        const unsigned short* __restrict__ zhi,
        const unsigned short* __restrict__ zlo,
        const unsigned short* __restrict__ ehi,
        const unsigned short* __restrict__ elo,
        const float* __restrict__ e2,
        int* __restrict__ rowCnt, int* __restrict__ rowCand) {
    __shared__ unsigned short Ah[8192], Al[8192], Bh[8192], Bl[8192]; // 64 KB

    const int t    = threadIdx.x;
    const int lane = t & 63;
    const int w    = t >> 6;
    const int wrow = w >> 1, wcol = w & 1;
    const int kc   = blockIdx.x & 7;
    const int rb   = blockIdx.x >> 3;
    const int n0   = rb * 128, k0 = kc * 128;
    const int c    = lane & 15, kq = lane >> 4;

    f32x4 acc[4][4];
#pragma unroll
    for (int rf = 0; rf < 4; ++rf)
#pragma unroll
        for (int cf = 0; cf < 4; ++cf)
            acc[rf][cf] = (f32x4){0.f, 0.f, 0.f, 0.f};

    for (int sl = 0; sl < 4; ++sl) {
        // stage 4 tiles x 16 KB: slot = i*256+t -> row = slot>>3, s16 = slot&7
#pragma unroll
        for (int i = 0; i < 4; ++i) {
            int slot = i * 256 + t;
            int row = slot >> 3, s16 = slot & 7;
            size_t aoff = (size_t)(n0 + row) * 256 + sl * 64 + s16 * 8;
            size_t boff = (size_t)(k0 + row) * 256 + sl * 64 + s16 * 8;
            int dbase = (i * 256 + w * 64) * 8;   // wave-uniform dest (u16 elems)
            gload16(zhi + aoff, &Ah[dbase]);
            gload16(zlo + aoff, &Al[dbase]);
            gload16(ehi + boff, &Bh[dbase]);
            gload16(elo + boff, &Bl[dbase]);
        }
        __syncthreads();
#pragma unroll
        for (int ks = 0; ks < 2; ++ks) {
            short8 ah[4], al[4], bh[4], bl[4];
#pragma unroll
            for (int rf = 0; rf < 4; ++rf) {
                int rl = wrow * 64 + rf * 16 + c;
                int sp = (ks * 4 + kq) ^ (rl & 7);
                ah[rf] = *(const short8*)&Ah[rl * 64 + sp * 8];
                al[rf] = *(const short8*)&Al[rl * 64 + sp * 8];
            }
#pragma unroll
            for (int cf = 0; cf < 4; ++cf) {
                int cl = wcol * 64 + cf * 16 + c;
                int sp = (ks * 4 + kq) ^ (cl & 7);
                bh[cf] = *(const short8*)&Bh[cl * 64 + sp * 8];
                bl[cf] = *(const short8*)&Bl[cl * 64 + sp * 8];
            }
#pragma unroll
            for (int rf = 0; rf < 4; ++rf)
#pragma unroll
                for (int cf = 0; cf < 4; ++cf) {
                    acc[rf][cf] = __builtin_amdgcn_mfma_f32_16x16x32_bf16(ah[rf], bh[cf], acc[rf][cf], 0, 0, 0);
                    acc[rf][cf] = __builtin_amdgcn_mfma_f32_16x16x32_bf16(al[rf], bh[cf], acc[rf][cf], 0, 0, 0);
                    acc[rf][cf] = __builtin_amdgcn_mfma_f32_16x16x32_bf16(ah[rf], bl[cf], acc[rf][cf], 0, 0, 0);
                }
        }
        __syncthreads();
    }

    // ---- epilogue: scores s = e2[k] - 2*ze (z2-free; row-constant shift) ----
    float e2r[4];
#pragma unroll
    for (int cf = 0; cf < 4; ++cf) e2r[cf] = e2[k0 + wcol * 64 + cf * 16 + c];

    float rmin[4][4];
#pragma unroll
    for (int rf = 0; rf < 4; ++rf)
#pragma unroll
        for (int reg = 0; reg < 4; ++reg) {
            float mm = 3.4e38f;
#pragma unroll
            for (int cf = 0; cf < 4; ++cf)
                mm = fminf(mm, fmaf(-2.f, acc[rf][cf][reg], e2r[cf]));
            rmin[rf][reg] = mm;
        }
#pragma unroll
    for (int m = 1; m < 16; m <<= 1)
#pragma unroll
        for (int rf = 0; rf < 4; ++rf)
#pragma unroll
            for (int reg = 0; reg < 4; ++reg)
                rmin[rf][reg] = fminf(rmin[rf][reg],
                                      __shfl_xor(rmin[rf][reg], m, 64));

#pragma unroll
    for (int rf = 0; rf < 4; ++rf)
#pragma unroll
        for (int cf = 0; cf < 4; ++cf)
#pragma unroll
            for (int reg = 0; reg < 4; ++reg) {
                float s = fmaf(-2.f, acc[rf][cf][reg], e2r[cf]);
                if (s <= rmin[rf][reg] + MARGIN) {
                    int n = n0 + wrow * 64 + rf * 16 + kq * 4 + reg;
                    int k = k0 + wcol * 64 + cf * 16 + c;
                    int pos = atomicAdd(&rowCnt[n], 1);
                    if (pos < RCAP) rowCand[n * RCAP + pos] = k;
                }
            }
}

// ---------------------------------------------------------------------------
// k_select: exact rescore. Wave per row-batch; lane ci rescores candidate ci
// with the VALIDATED path: per-lane ascending-d fp32 FMA chain (z loads are
// lane-broadcast), dist = fmaf(-2, ze, fl(z2+e2)); packed (distbits<<32|k)
// min == np argmin first-index tie-break. cnt>RCAP -> deterministic full
// 1024-code scan (16 codes/lane).
// ---------------------------------------------------------------------------
__global__ __launch_bounds__(256) void k_select(
        const float* __restrict__ z, const float* __restrict__ e,
        const float* __restrict__ z2a, const float* __restrict__ e2,
        const int* __restrict__ rowCnt, const int* __restrict__ rowCand,
        float* __restrict__ outIdx, int* __restrict__ wsIdx) {
    const int t = threadIdx.x, lane = t & 63, w = t >> 6;
    const int wid = blockIdx.x * 4 + w;       // 0..4095
    for (int rr = 0; rr < 8; ++rr) {
        const int n = wid * 8 + rr;
        const int cnt = rowCnt[n];
        const float* zrow = z + (size_t)(n >> 10) * (D_DIM * 1024) + (n & 1023);
        const float z2r = z2a[n];
        unsigned long long key = 0xFFFFFFFFFFFFFFFFULL;
        if (cnt <= RCAP) {
            if (lane < cnt) {
                int k = rowCand[n * RCAP + lane];
                const float* er = e + (size_t)k * D_DIM;
                float ze = 0.f;
#pragma unroll 8
                for (int d = 0; d < D_DIM; ++d)
                    ze = fmaf(zrow[(size_t)d * 1024], er[d], ze);
                float t1 = z2r + e2[k];
                float dist = fmaf(-2.f, ze, t1);
                key = ((unsigned long long)__float_as_uint(dist) << 32) |
                      (unsigned int)k;
            }
        } else {                      // deterministic fallback: full scan
            for (int j = 0; j < 16; ++j) {
                int k = lane * 16 + j;
                const float* er = e + (size_t)k * D_DIM;
                float ze = 0.f;
#pragma unroll 8
                for (int d = 0; d < D_DIM; ++d)
                    ze = fmaf(zrow[(size_t)d * 1024], er[d], ze);
                float t1 = z2r + e2[k];
                float dist = fmaf(-2.f, ze, t1);
                unsigned long long kk =
                    ((unsigned long long)__float_as_uint(dist) << 32) |
                    (unsigned int)k;
                if (kk < key) key = kk;
            }
        }
#pragma unroll
        for (int m = 1; m < 64; m <<= 1) {
            unsigned long long o = __shfl_xor(key, m, 64);
            if (o < key) key = o;
        }
        if (lane == 0) {
            int k = (int)(unsigned int)(key & 0xFFFFFFFFULL);
            outIdx[n] = (float)k;
            wsIdx[n]  = k;
        }
    }
}

// ---------------------------------------------------------------------------
// Epilogue: z_q gather + straight-through out + loss partial sums (validated).
// ---------------------------------------------------------------------------
__global__ __launch_bounds__(256) void k_epilogue(const float* __restrict__ z,
                                                  const float* __restrict__ e,
                                                  const int* __restrict__ wsIdx,
                                                  float* __restrict__ outZ,
                                                  float* __restrict__ lossAcc) {
    __shared__ float4 zq4[64][64];
    __shared__ int idxs[64];
    const int t = threadIdx.x;
    const int n0 = blockIdx.x * 64;
    const int b = n0 >> 10, nl0 = n0 & 1023;

    if (t < 64) idxs[t] = wsIdx[n0 + t];
    __syncthreads();

#pragma unroll
    for (int j = 0; j < 16; ++j) {
        int flat = j * 256 + t;
        int i  = flat >> 6;
        int c4 = flat & 63;
        float4 v = *(const float4*)(e + (size_t)idxs[i] * D_DIM + c4 * 4);
        zq4[i][c4 ^ (i & 7)] = v;
    }
    __syncthreads();

    const int i  = t & 63;
    const int dg = t >> 6;
    const float* zp = z    + (size_t)b * (D_DIM * 1024) + nl0 + i;
    float*       op = outZ + (size_t)b * (D_DIM * 1024) + nl0 + i;
    float s = 0.f;
#pragma unroll 4
    for (int c = 0; c < 16; ++c) {
        int c4 = dg * 16 + c;
        float4 qv = zq4[i][c4 ^ (i & 7)];
        int d = c4 * 4;
        float zv, df;
        zv = zp[(size_t)(d + 0) * 1024]; df = qv.x - zv; s = fmaf(df, df, s); op[(size_t)(d + 0) * 1024] = zv + df;
        zv = zp[(size_t)(d + 1) * 1024]; df = qv.y - zv; s = fmaf(df, df, s); op[(size_t)(d + 1) * 1024] = zv + df;
        zv = zp[(size_t)(d + 2) * 1024]; df = qv.z - zv; s = fmaf(df, df, s); op[(size_t)(d + 2) * 1024] = zv + df;
        zv = zp[(size_t)(d + 3) * 1024]; df = qv.w - zv; s = fmaf(df, df, s); op[(size_t)(d + 3) * 1024] = zv + df;
    }
#pragma unroll
    for (int off = 32; off > 0; off >>= 1) s += __shfl_down(s, off, 64);
    if ((t & 63) == 0) atomicAdd(lossAcc, s);
}

__global__ void k_final(const float* __restrict__ lossAcc,
                        float* __restrict__ outLoss) {
    float m = lossAcc[0] * (1.0f / 8388608.0f);
    outLoss[0] = m + 0.25f * m;
}

// ---------------------------------------------------------------------------
extern "C" void kernel_launch(void* const* d_in, const int* in_sizes, int n_in,
                              void* d_out, int out_size, void* d_ws, size_t ws_size,
                              hipStream_t stream) {
    const float* z = (const float*)d_in[0];   // (32,256,32,32)
    const float* e = (const float*)d_in[1];   // (1024,256)
    float* out     = (float*)d_out;
    float* outIdx  = out + 8388608;
    float* outLoss = out + 8421376;

    float* z2      = (float*)d_ws;                        // 32768 f
    float* e2      = z2 + 32768;                          // 1024 f
    float* lossAcc = e2 + 1024;                           // 1 f
    int*   rowCnt  = (int*)(lossAcc + 1);                 // 32768 i
    int*   rowCand = rowCnt + 32768;                      // 32768*32 i = 4 MB
    uintptr_t p = (uintptr_t)(rowCand + 32768 * RCAP);
    p = (p + 255) & ~(uintptr_t)255;
    unsigned short* zhi = (unsigned short*)p;             // 8,388,608 u16 = 16 MB
    unsigned short* zlo = zhi + 8388608;                  // 16 MB
    unsigned short* ehi = zlo + 8388608;                  // 262144 u16
    unsigned short* elo = ehi + 262144;                   // 262144 u16
    int*   wsIdx   = (int*)(elo + 262144);                // 32768 i

    k_prep<<<2228, 256, 0, stream>>>(z, e, z2, e2, zhi, zlo, ehi, elo,
                                     rowCnt, lossAcc);
    k_score<<<2048, 256, 0, stream>>>(zhi, zlo, ehi, elo, e2, rowCnt, rowCand);
    k_select<<<1024, 256, 0, stream>>>(z, e, z2, e2, rowCnt, rowCand,
                                       outIdx, wsIdx);
    k_epilogue<<<512, 256, 0, stream>>>(z, e, wsIdx, out, lossAcc);
    k_final<<<1, 1, 0, stream>>>(lossAcc, outLoss);
}

// Round 10
// 240.020 us; speedup vs baseline: 1.8061x; 1.4988x over previous
//
#include <hip/hip_runtime.h>

#define D_DIM 256
#define K_CODES 1024
#define MARGIN 4e-4f
#define RCAP 32

typedef __attribute__((ext_vector_type(8))) short short8;
typedef __attribute__((ext_vector_type(4))) float f32x4;

// RNE f32 -> bf16 bits (finite inputs; validated rounds 6-9)
__device__ __forceinline__ unsigned int bfr(float x) {
    unsigned int u = __float_as_uint(x);
    return (u + 0x7FFFu + ((u >> 16) & 1u)) >> 16;
}
__device__ __forceinline__ float bf2f(unsigned int b) {
    return __uint_as_float(b << 16);
}
__device__ __forceinline__ void gload16(const void* g, void* l) {
    __builtin_amdgcn_global_load_lds(
        (const __attribute__((address_space(1))) void*)g,
        (__attribute__((address_space(3))) void*)l, 16, 0, 0);
}

// ---------------------------------------------------------------------------
// k_prep: [0,128) z2 | [128,132) e2 | [132,2180) z split+transpose+swz |
//         [2180,2196) e split+swz | [2196,2228) rowCnt zero (+lossAcc)
// (unchanged from validated round 9)
// ---------------------------------------------------------------------------
__global__ __launch_bounds__(256) void k_prep(const float* __restrict__ z,
                                              const float* __restrict__ e,
                                              float* __restrict__ z2,
                                              float* __restrict__ e2,
                                              unsigned short* __restrict__ zhi,
                                              unsigned short* __restrict__ zlo,
                                              unsigned short* __restrict__ ehi,
                                              unsigned short* __restrict__ elo,
                                              int* __restrict__ rowCnt,
                                              float* __restrict__ lossAcc) {
    __shared__ float tile[64][65];
    const int bi = blockIdx.x;
    const int t  = threadIdx.x;
    if (bi < 128) {                    // ---- z2 ----
        int n = bi * 256 + t;
        int b = n >> 10, nl = n & 1023;
        const float* p = z + (size_t)b * (D_DIM * 1024) + nl;
        float s = 0.f;
#pragma unroll 8
        for (int d = 0; d < D_DIM; ++d) {
            float v = p[(size_t)d * 1024];
            s = fmaf(v, v, s);
        }
        z2[n] = s;
    } else if (bi < 132) {             // ---- e2 ----
        int k = (bi - 128) * 256 + t;
        const float4* p = (const float4*)(e + (size_t)k * D_DIM);
        float s = 0.f;
#pragma unroll 4
        for (int c = 0; c < D_DIM / 4; ++c) {
            float4 v = p[c];
            s = fmaf(v.x, v.x, s); s = fmaf(v.y, v.y, s);
            s = fmaf(v.z, v.z, s); s = fmaf(v.w, v.w, s);
        }
        e2[k] = s;
    } else if (bi < 2180) {            // ---- z split + transpose + swizzle ----
        int bb = bi - 132;
        int n0 = (bb & 511) * 64;
        int d0 = (bb >> 9) * 64;
        int b = n0 >> 10, nl0 = n0 & 1023;
#pragma unroll 4
        for (int i = 0; i < 16; ++i) {
            int flat = i * 256 + t;
            int dd = flat >> 6, j = flat & 63;
            tile[dd][j] = z[(size_t)b * (D_DIM * 1024) +
                            (size_t)(d0 + dd) * 1024 + nl0 + j];
        }
        __syncthreads();
#pragma unroll
        for (int i = 0; i < 4; ++i) {
            int flat = i * 256 + t;
            int row = flat >> 4, ch = flat & 15;
            int s8p = ch >> 1, half = ch & 1;
            int s8  = s8p ^ (row & 7);
            int ddl = s8 * 8 + half * 4;
            unsigned int h[4], l[4];
#pragma unroll
            for (int m2 = 0; m2 < 4; ++m2) {
                float v = tile[ddl + m2][row];
                h[m2] = bfr(v);
                l[m2] = bfr(v - bf2f(h[m2]));
            }
            uint2 ph = { h[0] | (h[1] << 16), h[2] | (h[3] << 16) };
            uint2 pl = { l[0] | (l[1] << 16), l[2] | (l[3] << 16) };
            size_t off = (size_t)(n0 + row) * 256 + d0 + s8p * 8 + half * 4;
            *(uint2*)(zhi + off) = ph;
            *(uint2*)(zlo + off) = pl;
        }
    } else if (bi < 2196) {            // ---- e split + swizzle ----
        int k0 = (bi - 2180) * 64;
#pragma unroll 4
        for (int i = 0; i < 16; ++i) {
            int flat = i * 256 + t;
            int row = flat >> 6, ch = flat & 63;
            int slab = ch >> 4, s8p = (ch >> 1) & 7, half = ch & 1;
            int s8 = s8p ^ (row & 7);
            int d  = slab * 64 + s8 * 8 + half * 4;
            float4 v = *(const float4*)(e + (size_t)(k0 + row) * 256 + d);
            unsigned int h0 = bfr(v.x), h1 = bfr(v.y), h2 = bfr(v.z), h3 = bfr(v.w);
            unsigned int l0 = bfr(v.x - bf2f(h0)), l1 = bfr(v.y - bf2f(h1));
            unsigned int l2 = bfr(v.z - bf2f(h2)), l3 = bfr(v.w - bf2f(h3));
            uint2 ph = { h0 | (h1 << 16), h2 | (h3 << 16) };
            uint2 pl = { l0 | (l1 << 16), l2 | (l3 << 16) };
            size_t off = (size_t)(k0 + row) * 256 + slab * 64 + s8p * 8 + half * 4;
            *(uint2*)(ehi + off) = ph;
            *(uint2*)(elo + off) = pl;
        }
    } else {                           // ---- rowCnt zero ----
        int bb = bi - 2196;
        if (bb == 0 && t == 0) lossAcc[0] = 0.f;
#pragma unroll
        for (int i = 0; i < 4; ++i)
            rowCnt[bb * 1024 + i * 256 + t] = 0;
    }
}

// ---------------------------------------------------------------------------
// k_score: split-bf16 MFMA GEMM, 128 rows x 128 codes x K=256 per block
// (validated round 9). CHANGE: candidates stored as uint2 {k, score_bits}
// so k_select can filter by global approx min before any exact rescore.
// ---------------------------------------------------------------------------
__global__ __launch_bounds__(256) void k_score(
        const unsigned short* __restrict__ zhi,
        const unsigned short* __restrict__ zlo,
        const unsigned short* __restrict__ ehi,
        const unsigned short* __restrict__ elo,
        const float* __restrict__ e2,
        int* __restrict__ rowCnt, uint2* __restrict__ rowCand) {
    __shared__ unsigned short Ah[8192], Al[8192], Bh[8192], Bl[8192]; // 64 KB

    const int t    = threadIdx.x;
    const int lane = t & 63;
    const int w    = t >> 6;
    const int wrow = w >> 1, wcol = w & 1;
    const int kc   = blockIdx.x & 7;
    const int rb   = blockIdx.x >> 3;
    const int n0   = rb * 128, k0 = kc * 128;
    const int c    = lane & 15, kq = lane >> 4;

    f32x4 acc[4][4];
#pragma unroll
    for (int rf = 0; rf < 4; ++rf)
#pragma unroll
        for (int cf = 0; cf < 4; ++cf)
            acc[rf][cf] = (f32x4){0.f, 0.f, 0.f, 0.f};

    for (int sl = 0; sl < 4; ++sl) {
#pragma unroll
        for (int i = 0; i < 4; ++i) {
            int slot = i * 256 + t;
            int row = slot >> 3, s16 = slot & 7;
            size_t aoff = (size_t)(n0 + row) * 256 + sl * 64 + s16 * 8;
            size_t boff = (size_t)(k0 + row) * 256 + sl * 64 + s16 * 8;
            int dbase = (i * 256 + w * 64) * 8;
            gload16(zhi + aoff, &Ah[dbase]);
            gload16(zlo + aoff, &Al[dbase]);
            gload16(ehi + boff, &Bh[dbase]);
            gload16(elo + boff, &Bl[dbase]);
        }
        __syncthreads();
#pragma unroll
        for (int ks = 0; ks < 2; ++ks) {
            short8 ah[4], al[4], bh[4], bl[4];
#pragma unroll
            for (int rf = 0; rf < 4; ++rf) {
                int rl = wrow * 64 + rf * 16 + c;
                int sp = (ks * 4 + kq) ^ (rl & 7);
                ah[rf] = *(const short8*)&Ah[rl * 64 + sp * 8];
                al[rf] = *(const short8*)&Al[rl * 64 + sp * 8];
            }
#pragma unroll
            for (int cf = 0; cf < 4; ++cf) {
                int cl = wcol * 64 + cf * 16 + c;
                int sp = (ks * 4 + kq) ^ (cl & 7);
                bh[cf] = *(const short8*)&Bh[cl * 64 + sp * 8];
                bl[cf] = *(const short8*)&Bl[cl * 64 + sp * 8];
            }
#pragma unroll
            for (int rf = 0; rf < 4; ++rf)
#pragma unroll
                for (int cf = 0; cf < 4; ++cf) {
                    acc[rf][cf] = __builtin_amdgcn_mfma_f32_16x16x32_bf16(ah[rf], bh[cf], acc[rf][cf], 0, 0, 0);
                    acc[rf][cf] = __builtin_amdgcn_mfma_f32_16x16x32_bf16(al[rf], bh[cf], acc[rf][cf], 0, 0, 0);
                    acc[rf][cf] = __builtin_amdgcn_mfma_f32_16x16x32_bf16(ah[rf], bl[cf], acc[rf][cf], 0, 0, 0);
                }
        }
        __syncthreads();
    }

    // ---- epilogue: s = e2[k] - 2*ze; capture s <= chunkmin + MARGIN ----
    float e2r[4];
#pragma unroll
    for (int cf = 0; cf < 4; ++cf) e2r[cf] = e2[k0 + wcol * 64 + cf * 16 + c];

    float rmin[4][4];
#pragma unroll
    for (int rf = 0; rf < 4; ++rf)
#pragma unroll
        for (int reg = 0; reg < 4; ++reg) {
            float mm = 3.4e38f;
#pragma unroll
            for (int cf = 0; cf < 4; ++cf)
                mm = fminf(mm, fmaf(-2.f, acc[rf][cf][reg], e2r[cf]));
            rmin[rf][reg] = mm;
        }
#pragma unroll
    for (int m = 1; m < 16; m <<= 1)
#pragma unroll
        for (int rf = 0; rf < 4; ++rf)
#pragma unroll
            for (int reg = 0; reg < 4; ++reg)
                rmin[rf][reg] = fminf(rmin[rf][reg],
                                      __shfl_xor(rmin[rf][reg], m, 64));

#pragma unroll
    for (int rf = 0; rf < 4; ++rf)
#pragma unroll
        for (int cf = 0; cf < 4; ++cf)
#pragma unroll
            for (int reg = 0; reg < 4; ++reg) {
                float s = fmaf(-2.f, acc[rf][cf][reg], e2r[cf]);
                if (s <= rmin[rf][reg] + MARGIN) {
                    int n = n0 + wrow * 64 + rf * 16 + kq * 4 + reg;
                    int k = k0 + wcol * 64 + cf * 16 + c;
                    int pos = atomicAdd(&rowCnt[n], 1);
                    if (pos < RCAP) {
                        uint2 cd; cd.x = (unsigned)k; cd.y = __float_as_uint(s);
                        rowCand[n * RCAP + pos] = cd;
                    }
                }
            }
}

// ---------------------------------------------------------------------------
// k_select: global-min filter, then exact rescore of survivors only.
// Per row: gmin = min of stored approx scores; survivors = {s <= gmin+MARGIN}.
// PROOF: non-survivor k has s_a(k) > gmin+M => d_ref(k) > d_ref(best
// survivor) + (M - 2*eps - 2*delta) > 0 (eps~4.5e-5 approx+eval, delta~5e-5
// ref rounding; M=4e-4) => cannot win or tie. Survivors subset of captured:
// gmin <= chunkmin, fl monotone. popcount==1 => that k IS the ref argmin.
// Else: exact rescore per survivor (validated ascending-d fp32 chain,
// dist = fmaf(-2, ze, fl(z2+e2))), packed (distbits<<32|k) min == np argmin
// first-index tie-break. cnt > RCAP => deterministic full 1024-code scan.
// ---------------------------------------------------------------------------
__global__ __launch_bounds__(256) void k_select(
        const float* __restrict__ z, const float* __restrict__ e,
        const float* __restrict__ z2a, const float* __restrict__ e2,
        const int* __restrict__ rowCnt, const uint2* __restrict__ rowCand,
        float* __restrict__ outIdx, int* __restrict__ wsIdx) {
    const int t = threadIdx.x, lane = t & 63, w = t >> 6;
    const int wid = blockIdx.x * 4 + w;       // 0..4095
    for (int rr = 0; rr < 8; ++rr) {
        const int n = wid * 8 + rr;
        const int cnt = rowCnt[n];
        const float* zrow = z + (size_t)(n >> 10) * (D_DIM * 1024) + (n & 1023);
        unsigned long long key = 0xFFFFFFFFFFFFFFFFULL;
        if (cnt <= RCAP) {
            float s = 3.4e38f;
            int   k = 0;
            if (lane < cnt) {
                uint2 cd = rowCand[n * RCAP + lane];
                k = (int)cd.x;
                s = __uint_as_float(cd.y);
            }
            float gmin = s;
#pragma unroll
            for (int m = 1; m < 64; m <<= 1)
                gmin = fminf(gmin, __shfl_xor(gmin, m, 64));
            bool surv = (lane < cnt) && (s <= gmin + MARGIN);
            unsigned long long bal = __ballot(surv);
            if (__popcll(bal) == 1) {            // sole survivor == argmin
                if (surv) { outIdx[n] = (float)k; wsIdx[n] = k; }
                continue;                         // bal wave-uniform
            }
            if (surv) {
                const float* er = e + (size_t)k * D_DIM;
                float ze = 0.f;
#pragma unroll 8
                for (int d = 0; d < D_DIM; ++d)
                    ze = fmaf(zrow[(size_t)d * 1024], er[d], ze);
                float t1 = z2a[n] + e2[k];
                float dist = fmaf(-2.f, ze, t1);
                key = ((unsigned long long)__float_as_uint(dist) << 32) |
                      (unsigned int)k;
            }
        } else {                      // deterministic fallback: full scan
            const float z2r = z2a[n];
            for (int j = 0; j < 16; ++j) {
                int k = lane * 16 + j;
                const float* er = e + (size_t)k * D_DIM;
                float ze = 0.f;
#pragma unroll 8
                for (int d = 0; d < D_DIM; ++d)
                    ze = fmaf(zrow[(size_t)d * 1024], er[d], ze);
                float t1 = z2r + e2[k];
                float dist = fmaf(-2.f, ze, t1);
                unsigned long long kk =
                    ((unsigned long long)__float_as_uint(dist) << 32) |
                    (unsigned int)k;
                if (kk < key) key = kk;
            }
        }
#pragma unroll
        for (int m = 1; m < 64; m <<= 1) {
            unsigned long long o = __shfl_xor(key, m, 64);
            if (o < key) key = o;
        }
        if (lane == 0) {
            int k = (int)(unsigned int)(key & 0xFFFFFFFFULL);
            outIdx[n] = (float)k;
            wsIdx[n]  = k;
        }
    }
}

// ---------------------------------------------------------------------------
// Epilogue: z_q gather + straight-through out + loss partial sums (validated).
// ---------------------------------------------------------------------------
__global__ __launch_bounds__(256) void k_epilogue(const float* __restrict__ z,
                                                  const float* __restrict__ e,
                                                  const int* __restrict__ wsIdx,
                                                  float* __restrict__ outZ,
                                                  float* __restrict__ lossAcc) {
    __shared__ float4 zq4[64][64];
    __shared__ int idxs[64];
    const int t = threadIdx.x;
    const int n0 = blockIdx.x * 64;
    const int b = n0 >> 10, nl0 = n0 & 1023;

    if (t < 64) idxs[t] = wsIdx[n0 + t];
    __syncthreads();

#pragma unroll
    for (int j = 0; j < 16; ++j) {
        int flat = j * 256 + t;
        int i  = flat >> 6;
        int c4 = flat & 63;
        float4 v = *(const float4*)(e + (size_t)idxs[i] * D_DIM + c4 * 4);
        zq4[i][c4 ^ (i & 7)] = v;
    }
    __syncthreads();

    const int i  = t & 63;
    const int dg = t >> 6;
    const float* zp = z    + (size_t)b * (D_DIM * 1024) + nl0 + i;
    float*       op = outZ + (size_t)b * (D_DIM * 1024) + nl0 + i;
    float s = 0.f;
#pragma unroll 4
    for (int c = 0; c < 16; ++c) {
        int c4 = dg * 16 + c;
        float4 qv = zq4[i][c4 ^ (i & 7)];
        int d = c4 * 4;
        float zv, df;
        zv = zp[(size_t)(d + 0) * 1024]; df = qv.x - zv; s = fmaf(df, df, s); op[(size_t)(d + 0) * 1024] = zv + df;
        zv = zp[(size_t)(d + 1) * 1024]; df = qv.y - zv; s = fmaf(df, df, s); op[(size_t)(d + 1) * 1024] = zv + df;
        zv = zp[(size_t)(d + 2) * 1024]; df = qv.z - zv; s = fmaf(df, df, s); op[(size_t)(d + 2) * 1024] = zv + df;
        zv = zp[(size_t)(d + 3) * 1024]; df = qv.w - zv; s = fmaf(df, df, s); op[(size_t)(d + 3) * 1024] = zv + df;
    }
#pragma unroll
    for (int off = 32; off > 0; off >>= 1) s += __shfl_down(s, off, 64);
    if ((t & 63) == 0) atomicAdd(lossAcc, s);
}

__global__ void k_final(const float* __restrict__ lossAcc,
                        float* __restrict__ outLoss) {
    float m = lossAcc[0] * (1.0f / 8388608.0f);
    outLoss[0] = m + 0.25f * m;
}

// ---------------------------------------------------------------------------
extern "C" void kernel_launch(void* const* d_in, const int* in_sizes, int n_in,
                              void* d_out, int out_size, void* d_ws, size_t ws_size,
                              hipStream_t stream) {
    const float* z = (const float*)d_in[0];   // (32,256,32,32)
    const float* e = (const float*)d_in[1];   // (1024,256)
    float* out     = (float*)d_out;
    float* outIdx  = out + 8388608;
    float* outLoss = out + 8421376;

    float* z2      = (float*)d_ws;                        // 32768 f
    float* e2      = z2 + 32768;                          // 1024 f
    float* lossAcc = e2 + 1024;                           // 1 f
    int*   rowCnt  = (int*)(lossAcc + 1);                 // 32768 i
    uintptr_t p = (uintptr_t)(rowCnt + 32768);
    p = (p + 255) & ~(uintptr_t)255;
    uint2* rowCand = (uint2*)p;                           // 32768*32 uint2 = 8 MB
    unsigned short* zhi = (unsigned short*)(rowCand + 32768 * RCAP); // 16 MB
    unsigned short* zlo = zhi + 8388608;                  // 16 MB
    unsigned short* ehi = zlo + 8388608;                  // 512 KB
    unsigned short* elo = ehi + 262144;                   // 512 KB
    int*   wsIdx   = (int*)(elo + 262144);                // 32768 i

    k_prep<<<2228, 256, 0, stream>>>(z, e, z2, e2, zhi, zlo, ehi, elo,
                                     rowCnt, lossAcc);
    k_score<<<2048, 256, 0, stream>>>(zhi, zlo, ehi, elo, e2, rowCnt, rowCand);
    k_select<<<1024, 256, 0, stream>>>(z, e, z2, e2, rowCnt, rowCand,
                                       outIdx, wsIdx);
    k_epilogue<<<512, 256, 0, stream>>>(z, e, wsIdx, out, lossAcc);
    k_final<<<1, 1, 0, stream>>>(lossAcc, outLoss);
}